// Round 9
// baseline (2039.035 us; speedup 1.0000x reference)
//
#include <hip/hip_runtime.h>
#include <hip/hip_bf16.h>

#define NSITES 256
#define NM 128        // nup == ndn
#define NMODES 512

typedef unsigned long long u64;
typedef unsigned int u32;

#define REP8(M)    M(0) M(1) M(2) M(3) M(4) M(5) M(6) M(7)
#define REP8P(M,P) M(0,P) M(1,P) M(2,P) M(3,P) M(4,P) M(5,P) M(6,P) M(7,P)

// Integer DPP max step (all-VALU; int compare avoids denormal-flush hazards
// on bit-packed float keys).
template<int CTRL>
__device__ __forceinline__ int dpp_imax(int x) {
  const int y = __builtin_amdgcn_update_dpp(x, x, CTRL, 0xF, 0xF, false);
  return x > y ? x : y;
}
// Wave-wide int max, returned as a uniform (SGPR) value.
__device__ __forceinline__ int wave_imax_key(int x) {
  x = dpp_imax<0x128>(x);   // row_ror:8
  x = dpp_imax<0x124>(x);   // row_ror:4
  x = dpp_imax<0x122>(x);   // row_ror:2
  x = dpp_imax<0x121>(x);   // row_ror:1 -> each row-of-16 reduced
  x = dpp_imax<0x142>(x);   // row_bcast15
  x = dpp_imax<0x143>(x);   // row_bcast31 -> lane 63 has global max
  return __builtin_amdgcn_readfirstlane(__builtin_amdgcn_readlane(x, 63));
}
// Read element p (0..127) of a column stored as (x1: rows 0..63, x2: 64..127).
__device__ __forceinline__ float rl2(float x1, float x2, int p) {
  const int v1 = __builtin_amdgcn_readlane(__float_as_int(x1), p & 63);
  const int v2 = __builtin_amdgcn_readlane(__float_as_int(x2), p & 63);
  return __int_as_float(p < 64 ? v1 : v2);
}
__device__ __forceinline__ float bperm(int byteidx, float v) {
  return __int_as_float(__builtin_amdgcn_ds_bpermute(byteidx, __float_as_int(v)));
}

// One block per (batch, spin). 256 threads, register-resident 128x128 LU with
// partial pivoting, pivot-retirement (no physical swaps).
// TRANSPOSED mapping vs R5: ty = t&15, tx = t>>4. Thread owns
// a[II][JJ] = A[II*16+ty][JJ*16+tx]. Consequence: the 16 threads sharing tx
// (who all need the same pivot-row fragment) are IN THE SAME WAVE as the
// pivot-row owner (thread (tx, p&15) at lane (lane&0x30)|(p&15)) -> pivot row
// is broadcast by wave-local ds_bpermute. NO LDS staging of the pivot row, so
// the stage->barrier->read round-trip is off the critical path. The barrier
// (1/column) only orders the 2-step-lookahead pivot-COLUMN publish (colbuf).
// Argmax: bit-packed integer keys (|c| mantissa top bits | row index) + DPP
// integer max -> index = low 7 bits; no ballots.
// ALL register indices are preprocessor literals (SROA runs before unrolling).
__global__ __launch_bounds__(256, 2) void lu_kernel(
    const int* __restrict__ n, const float* __restrict__ phi_up,
    const float* __restrict__ phi_dn, float* __restrict__ ws, int B)
{
  __shared__ int occ[NSITES];
  __shared__ int wcnt[4];
  __shared__ float colbuf[2][NM];
  __shared__ int ipiv[NM];

  const int t = threadIdx.x;
  const int ty = t & 15, tx = t >> 4;     // TRANSPOSED vs R5
  const int lane = t & 63, wv = t >> 6;
  const int bs = blockIdx.x;
  const int b = bs >> 1, spin = bs & 1;
  const int* nn = n + b * NMODES + spin * NSITES;
  const float* phi = spin ? phi_dn : phi_up;

  // ---- occupied-site list (exactly NM entries, ascending) ----
  {
    int v = nn[t];
    u64 m = __ballot(v != 0);
    if (lane == 0) wcnt[wv] = __popcll(m);
    __syncthreads();
    int off = 0;
    for (int w = 0; w < wv; ++w) off += wcnt[w];
    if (v) occ[off + __popcll(m & ((1ull << lane) - 1))] = t;
    __syncthreads();
  }

  // ---- gather matrix into registers (static indices only) ----
  float a[8][8];
#define GATH(II) { const float* pr_ = phi + occ[(II)*16 + ty] * NM; \
  a[II][0] = pr_[0*16+tx]; a[II][1] = pr_[1*16+tx]; \
  a[II][2] = pr_[2*16+tx]; a[II][3] = pr_[3*16+tx]; \
  a[II][4] = pr_[4*16+tx]; a[II][5] = pr_[5*16+tx]; \
  a[II][6] = pr_[6*16+tx]; a[II][7] = pr_[7*16+tx]; }
  REP8(GATH)
#undef GATH

  // ---- prologue: col 0 -> colbuf[0], col 1 -> colbuf[1] ----
#define PUBP(II, DST) DST[(II)*16 + ty] = a[II][0];
  if (tx == 0) { float* d_ = &colbuf[0][0]; REP8P(PUBP, d_) }
  if (tx == 1) { float* d_ = &colbuf[1][0]; REP8P(PUBP, d_) }
#undef PUBP
  __syncthreads();

  float c1 = colbuf[0][lane];
  float c2 = colbuf[0][lane + 64];
  int r1 = 0, r2 = 0;           // retirement flags for rows lane, lane+64
  float l2sum = 0.f;
  int sb = 0;
  const int bidx0 = (ty) << 2;        // bpermute byte-indices for multipliers
  const int bidx1 = (16 + ty) << 2;
  const int bidx2 = (32 + ty) << 2;
  const int bidx3 = (48 + ty) << 2;

  for (int k = 0; k < NM; ++k) {
    const int cur = k & 1;
    __syncthreads();   // orders prev-step colbuf publish vs this-step reads

    // prefetch next pivot column (used late in P2; latency hides under argmax)
    const float d1 = colbuf[cur ^ 1][lane];
    const float d2 = colbuf[cur ^ 1][lane + 64];

    // ---- bit-packed integer argmax over active rows ----
    const int ka1 = r1 ? 0 : ((__float_as_int(c1) & 0x7FFFFF80) | lane);
    const int ka2 = r2 ? 0 : ((__float_as_int(c2) & 0x7FFFFF80) | (lane + 64));
    const int key = wave_imax_key(ka1 > ka2 ? ka1 : ka2);
    const int p = key & 127;
    const float pivv = rl2(c1, c2, p);
    const float rpiv = __builtin_amdgcn_rcpf(pivv);
    r1 |= (p == lane);
    r2 |= (p == lane + 64);
    const float m1 = r1 ? 0.f : c1 * rpiv;   // retired + pivot rows -> m = 0
    const float m2 = r2 ? 0.f : c2 * rpiv;
    if (t == 0) ipiv[k] = p;
    l2sum += __log2f(fabsf(pivv));
    sb ^= (int)(__float_as_uint(pivv) >> 31);

    if (k < NM - 1) {
      // ---- pivot row -> per-lane temps (uniform switch), then wave-local
      //      bpermute from the owner lane (lane&0x30)|(p&15) ----
      float w0, w1, w2, w3, w4, w5, w6, w7;
      switch (p >> 4) {
#define CPW(II) case II: w0=a[II][0]; w1=a[II][1]; w2=a[II][2]; w3=a[II][3]; \
  w4=a[II][4]; w5=a[II][5]; w6=a[II][6]; w7=a[II][7]; break;
        REP8(CPW)
#undef CPW
      }
      const int idxP = ((lane & 0x30) | (p & 15)) << 2;

      // multipliers for my 8 rows (II*16+ty) via wave-local bpermute
      float mI[8];
      mI[0] = bperm(bidx0, m1); mI[1] = bperm(bidx1, m1);
      mI[2] = bperm(bidx2, m1); mI[3] = bperm(bidx3, m1);
      mI[4] = bperm(bidx0, m2); mI[5] = bperm(bidx1, m2);
      mI[6] = bperm(bidx2, m2); mI[7] = bperm(bidx3, m2);

      // rank-1 update of columns >= k+1 (block-trimmed)
      const int T = (k + 1) >> 4;
      float pr[8];
#define PRE(JJ, KB) if ((JJ) >= (KB)) pr[JJ] = bperm(idxP, w##JJ);
#define UPDROW(II, KB) { \
  if (0 >= (KB)) a[II][0] = fmaf(-mI[II], pr[0], a[II][0]); \
  if (1 >= (KB)) a[II][1] = fmaf(-mI[II], pr[1], a[II][1]); \
  if (2 >= (KB)) a[II][2] = fmaf(-mI[II], pr[2], a[II][2]); \
  if (3 >= (KB)) a[II][3] = fmaf(-mI[II], pr[3], a[II][3]); \
  if (4 >= (KB)) a[II][4] = fmaf(-mI[II], pr[4], a[II][4]); \
  if (5 >= (KB)) a[II][5] = fmaf(-mI[II], pr[5], a[II][5]); \
  if (6 >= (KB)) a[II][6] = fmaf(-mI[II], pr[6], a[II][6]); \
  if (7 >= (KB)) a[II][7] = fmaf(-mI[II], pr[7], a[II][7]); }
#define LUCASE(KB) case KB: { REP8P(PRE, KB) REP8P(UPDROW, KB) } break;
      switch (T) {
        REP8(LUCASE)
      }
#undef LUCASE
#undef UPDROW
#undef PRE

      // advance pivot-column window: col k+1 (prefetched, through k-1) -> k
      const float ud = rl2(d1, d2, p);
      c1 = fmaf(-m1, ud, d1);
      c2 = fmaf(-m2, ud, d2);

      // publish col k+2 (through k, post-update) into colbuf[cur]
      if (k < NM - 2) {
        const int cn = k + 2;
        if (tx == (cn & 15)) {
          float* dst = &colbuf[cur][0];
          switch (cn >> 4) {
#define PUBJ(JJ) case JJ: \
  dst[0*16+ty]=a[0][JJ]; dst[1*16+ty]=a[1][JJ]; dst[2*16+ty]=a[2][JJ]; dst[3*16+ty]=a[3][JJ]; \
  dst[4*16+ty]=a[4][JJ]; dst[5*16+ty]=a[5][JJ]; dst[6*16+ty]=a[6][JJ]; dst[7*16+ty]=a[7][JJ]; break;
            REP8(PUBJ)
#undef PUBJ
          }
        }
      }
    }
  }

  // ---- permutation parity from pivot sequence (inversion count) ----
  __syncthreads();
  int inv = 0;
  if (t < NM) {
    const int my = ipiv[t];
    for (int l = t + 1; l < NM; ++l) inv += (my > ipiv[l]) ? 1 : 0;
  }
  const u64 bal = __ballot((t < NM) && (inv & 1));
  if (lane == 0) wcnt[wv] = __popcll(bal);
  __syncthreads();

  if (t == 0) {
    const int par = (wcnt[0] + wcnt[1] + wcnt[2] + wcnt[3]) & 1;
    const int s = (sb ^ par) & 1;
    ws[B + spin * B + b] = l2sum * 0.6931471805599453f;   // logabs: [B, 3B)
    ws[3 * B + spin * B + b] = s ? -1.f : 1.f;            // sign:   [3B, 5B)
  }
}

// One block per batch: log_j = -0.5 * sum_{i occ} sum_c v[i][c] * nf[c]
__global__ __launch_bounds__(256) void jastrow_kernel(
    const int* __restrict__ n, const float* __restrict__ v,
    float* __restrict__ ws, int B)
{
  __shared__ int occ[256];
  __shared__ float nf[NMODES];
  __shared__ int wcnt[8];
  __shared__ float red[256];
  const int t = threadIdx.x, b = blockIdx.x;
  const int lane = t & 63, wv = t >> 6;
  const int* nn = n + b * NMODES;
  int v0 = nn[t], v1 = nn[256 + t];
  nf[t] = (float)v0;
  nf[256 + t] = (float)v1;
  u64 m0 = __ballot(v0 != 0), m1 = __ballot(v1 != 0);
  if (lane == 0) { wcnt[wv] = __popcll(m0); wcnt[4 + wv] = __popcll(m1); }
  __syncthreads();
  int off0 = 0;
  for (int w = 0; w < wv; ++w) off0 += wcnt[w];
  int base1 = wcnt[0] + wcnt[1] + wcnt[2] + wcnt[3];
  int off1 = base1;
  for (int w = 0; w < wv; ++w) off1 += wcnt[4 + w];
  if (v0) occ[off0 + __popcll(m0 & ((1ull << lane) - 1))] = t;
  if (v1) occ[off1 + __popcll(m1 & ((1ull << lane) - 1))] = 256 + t;
  __syncthreads();

  float acc = 0.f;
  for (int r = wv * 64; r < wv * 64 + 64; ++r) {
    const float* row = v + occ[r] * NMODES;   // occ[r] wave-uniform -> broadcast
#pragma unroll
    for (int cc = 0; cc < 8; ++cc) {
      int c = cc * 64 + lane;                 // coalesced 256B per iter
      acc += row[c] * nf[c];
    }
  }
  red[t] = acc;
  __syncthreads();
  for (int s = 128; s >= 1; s >>= 1) {
    if (t < s) red[t] += red[t + s];
    __syncthreads();
  }
  if (t == 0) ws[b] = -0.5f * red[0];
}

__global__ void finalize_kernel(const float* __restrict__ ws,
                                float* __restrict__ out, int B)
{
  int b = blockIdx.x * 256 + threadIdx.x;
  if (b < B) {
    float lj = ws[b];
    float la_u = ws[B + b], la_d = ws[2 * B + b];
    float s_u = ws[3 * B + b], s_d = ws[4 * B + b];
    out[b] = s_u * s_d;
    out[B + b] = lj + la_u + la_d;
  }
}

extern "C" void kernel_launch(void* const* d_in, const int* in_sizes, int n_in,
                              void* d_out, int out_size, void* d_ws, size_t ws_size,
                              hipStream_t stream) {
  const int* n = (const int*)d_in[0];
  const float* phi_up = (const float*)d_in[1];
  const float* phi_dn = (const float*)d_in[2];
  const float* v = (const float*)d_in[3];
  float* out = (float*)d_out;
  float* ws = (float*)d_ws;
  const int B = in_sizes[0] / NMODES;  // 4096

  jastrow_kernel<<<B, 256, 0, stream>>>(n, v, ws, B);
  lu_kernel<<<2 * B, 256, 0, stream>>>(n, phi_up, phi_dn, ws, B);
  finalize_kernel<<<(B + 255) / 256, 256, 0, stream>>>(ws, out, B);
}